// Round 18
// baseline (1048.061 us; speedup 1.0000x reference)
//
#include <hip/hip_runtime.h>

// Batched QP via FISTA on the dual, Q = I (reference hardcodes eye(64)).
//
// R18 = R17 (best: rocprof 1243us, VGPR 32, occ 90%) + two register-neutral
// scheduling levers:
//  (1) #pragma unroll 2 on the main loop: pipelines the per-iter kCoef s_load
//      under compute, halves loop-branch overhead. Temporaries are phase-
//      local -> register-neutral.
//  (2) s_setprio(1) around each FMA+reduce cluster (T5): 4 independent
//      blocks/CU at drifting phases = the wave-role-diversity regime where
//      setprio paid +4-7% (attn, m191). Compute-phase waves get priority
//      over barrier-waiting waves.
// Ledger: arch-VGPR <= 32 and fewer inst/LDS-ops wins (R7->R9 DPP -463us,
// R9->R17 probe/fold/peel -110us); any register increase loses (R15 pins
// -60us, R16 4-chains -110us, R10 G-form -400us).

constexpr double csqrt_(double x) {
  double g = x * 0.5 + 0.5;
  for (int i = 0; i < 40; ++i) g = 0.5 * (g + x / g);
  return g;
}
struct CoefT { float c[200]; };
constexpr CoefT make_coefs() {
  CoefT T{};
  double t = 1.0;
  for (int k = 0; k < 200; ++k) {
    double tn = 0.5 * (1.0 + csqrt_(1.0 + 4.0 * t * t));
    T.c[k] = (float)((t - 1.0) / tn);
    t = tn;
  }
  return T;
}
__device__ constexpr CoefT kCoef = make_coefs();

__device__ __forceinline__ float dpp_add_xor1(float v) {
  int r = __builtin_amdgcn_update_dpp(0, __float_as_int(v), 0xB1, 0xF, 0xF, true);
  return v + __int_as_float(r);
}
__device__ __forceinline__ float dpp_add_xor2(float v) {
  int r = __builtin_amdgcn_update_dpp(0, __float_as_int(v), 0x4E, 0xF, 0xF, true);
  return v + __int_as_float(r);
}
__device__ __forceinline__ float swz_add_xor4(float v) {
  int r = __builtin_amdgcn_ds_swizzle(__float_as_int(v), 0x101F);
  return v + __int_as_float(r);
}

__global__ __launch_bounds__(512)
void qp_fista_kernel(const float* __restrict__ A,
                     const float* __restrict__ x,
                     const float* __restrict__ b,
                     float* __restrict__ out) {
  const int batch = blockIdx.x;
  const int tid = threadIdx.x;
  const int w = tid >> 6;   // wave 0..7

  __shared__ __align__(16) float tile[8192];  // A staging; later overlaid

  const float* Ag = A + (size_t)batch * 8192;

  // ---- stage A into LDS, coalesced float4 ----
  {
    const float4* Ag4 = (const float4*)Ag;
    float4* t4 = (float4*)tile;
#pragma unroll
    for (int k = 0; k < 4; ++k) t4[tid + k * 512] = Ag4[tid + k * 512];
  }
  __syncthreads();

  // ---- register views (16 + 16 floats per thread) ----
  const int r  = tid >> 2;  // mv2: row owned
  const int cq = tid & 3;   // mv2: col-quarter (quad lane bits 0-1)
  float Ar[16];
  {
    const float4* t4 = (const float4*)tile;
#pragma unroll
    for (int j = 0; j < 4; ++j) {
      float4 v = t4[r * 16 + cq * 4 + j];
      Ar[4 * j + 0] = v.x; Ar[4 * j + 1] = v.y;
      Ar[4 * j + 2] = v.z; Ar[4 * j + 3] = v.w;
    }
  }
  const int c  = tid >> 3;  // mv1: col owned
  const int rq = tid & 7;   // mv1: row-eighth (lane bits 0-2)
  float Ac[16];
#pragma unroll
  for (int i = 0; i < 16; ++i) Ac[i] = tile[(rq * 16 + i) * 64 + c];

  // sum of squares (Ar covers each A element exactly once across 512 threads)
  float ss = 0.f;
#pragma unroll
  for (int i = 0; i < 16; ++i) ss = fmaf(Ar[i], Ar[i], ss);
#pragma unroll
  for (int d = 1; d < 64; d <<= 1) ss += __shfl_xor(ss, d, 64);  // one-time

  __syncthreads();  // register extraction done; overlay small buffers

  float* zbuf = tile;         // 4 sections x 20 dw (z[0..63]); banks 0/20/8/28
  float* ybuf = tile + 96;    // 8 sections x 20 dw (y[0..127]); 8 distinct banks
  float* wsb  = tile + 272;   // 8 per-wave sum-of-squares

  if ((tid & 63) == 0) wsb[w] = ss;
  const float breg = b[(size_t)batch * 128 + r];
  const float xreg = x[(size_t)batch * 64 + c];
  if (rq == 0) zbuf[(c >> 4) * 20 + (c & 15)] = xreg;  // z0 = primal(0) = x
  __syncthreads();

  float sum8 = 0.f;
#pragma unroll
  for (int i = 0; i < 8; ++i) sum8 += wsb[i];
  const float eta = 1.0f / fmaxf(8.0f * sum8, 1e-12f);  // ||Qinv||_F = 8
  const float yb0 = eta * breg;  // folded: y + eta*(acc-b) = fma(eta,acc,y-yb0)

  const float4* zs = (const float4*)(zbuf + cq * 20);
  const float4* ys = (const float4*)(ybuf + rq * 20);
  float* ywr = ybuf + w * 20 + (r & 15);               // r>>4 == w
  float* zwr = zbuf + (c >> 4) * 20 + (c & 15);

  float lam = 0.f, y = 0.f;

#pragma unroll 2
  for (int it = 0; it < 199; ++it) {
    const float coef = kCoef.c[it];

    // ---- mv2: (Az)[r], 2 chains (R9-proven) ----
    __builtin_amdgcn_s_setprio(1);
    float p0 = 0.f, p1 = 0.f;
#pragma unroll
    for (int j = 0; j < 4; ++j) {
      float4 zz = zs[j];
      p0 = fmaf(Ar[4 * j + 0], zz.x, p0);
      p1 = fmaf(Ar[4 * j + 1], zz.y, p1);
      p0 = fmaf(Ar[4 * j + 2], zz.z, p0);
      p1 = fmaf(Ar[4 * j + 3], zz.w, p1);
    }
    float acc = p0 + p1;
    acc = dpp_add_xor1(acc);
    acc = dpp_add_xor2(acc);           // full row dot, replicated in quad
    float ln = fmaxf(0.f, fmaf(eta, acc, y - yb0));
    float yn = fmaf(coef, ln - lam, ln);
    __builtin_amdgcn_s_setprio(0);
    lam = ln; y = yn;
    if (cq == 0) *ywr = yn;
    __syncthreads();  // ybuf ready

    // ---- mv1: (A^T y)[c], 2 chains ----
    __builtin_amdgcn_s_setprio(1);
    float q0 = 0.f, q1 = 0.f;
#pragma unroll
    for (int j = 0; j < 4; ++j) {
      float4 yy = ys[j];
      q0 = fmaf(Ac[4 * j + 0], yy.x, q0);
      q1 = fmaf(Ac[4 * j + 1], yy.y, q1);
      q0 = fmaf(Ac[4 * j + 2], yy.z, q0);
      q1 = fmaf(Ac[4 * j + 3], yy.w, q1);
    }
    float s = q0 + q1;
    s = dpp_add_xor1(s);
    s = dpp_add_xor2(s);
    s = swz_add_xor4(s);               // full col dot over 8 lanes
    __builtin_amdgcn_s_setprio(0);
    if (rq == 0) *zwr = xreg - s;      // z = x - A^T y
    __syncthreads();
  }

  // ---- peeled it = 199: write lam, final primal ----
  {
    float p0 = 0.f, p1 = 0.f;
#pragma unroll
    for (int j = 0; j < 4; ++j) {
      float4 zz = zs[j];
      p0 = fmaf(Ar[4 * j + 0], zz.x, p0);
      p1 = fmaf(Ar[4 * j + 1], zz.y, p1);
      p0 = fmaf(Ar[4 * j + 2], zz.z, p0);
      p1 = fmaf(Ar[4 * j + 3], zz.w, p1);
    }
    float acc = p0 + p1;
    acc = dpp_add_xor1(acc);
    acc = dpp_add_xor2(acc);
    float ln = fmaxf(0.f, fmaf(eta, acc, y - yb0));
    if (cq == 0) *ywr = ln;            // final lambda
    __syncthreads();

    float q0 = 0.f, q1 = 0.f;
#pragma unroll
    for (int j = 0; j < 4; ++j) {
      float4 yy = ys[j];
      q0 = fmaf(Ac[4 * j + 0], yy.x, q0);
      q1 = fmaf(Ac[4 * j + 1], yy.y, q1);
      q0 = fmaf(Ac[4 * j + 2], yy.z, q0);
      q1 = fmaf(Ac[4 * j + 3], yy.w, q1);
    }
    float s = q0 + q1;
    s = dpp_add_xor1(s);
    s = dpp_add_xor2(s);
    s = swz_add_xor4(s);
    if (rq == 0) *zwr = xreg - s;      // z* = x - A^T lam
    __syncthreads();
  }

  if (tid < 64) {
    out[(size_t)batch * 64 + tid] = zbuf[(tid >> 4) * 20 + (tid & 15)];
  }
}

extern "C" void kernel_launch(void* const* d_in, const int* in_sizes, int n_in,
                              void* d_out, int out_size, void* d_ws, size_t ws_size,
                              hipStream_t stream) {
  // setup_inputs order: Q (ignored: identity), A, x, b
  const float* A = (const float*)d_in[1];
  const float* x = (const float*)d_in[2];
  const float* b = (const float*)d_in[3];
  float* out = (float*)d_out;
  qp_fista_kernel<<<dim3(8192), dim3(512), 0, stream>>>(A, x, b, out);
}

// Round 19
// 1000.807 us; speedup vs baseline: 1.0472x; 1.0472x over previous
//
#include <hip/hip_runtime.h>

// Batched QP via FISTA on the dual, Q = I (reference hardcodes eye(64)).
//
// R19 = R18 base + mv2 LDS-read restructure (the LDS-pipe-bound theory).
// Evidence: wall ~1855 cy/iter-round vs VALU model ~832/SIMD but LDS model
// ~352 instr/CU-iter x ~5cy ~= 1760 -> LDS pipe (per-CU shared) is the
// binder. R7->R9's only big win (-463us) cut LDS ops; register changes
// never moved the needle.
// mv2 re-map: thread owns A[4rg..4rg+3][4cs..4cs+3] (rg=tid>>4, cs=tid&15):
//   ONE ds_read_b128 of z[4cs..4cs+3] (was 4 reads) -> 16 FMA into 4 row-accs
//   -> pair-swap butterfly (sel+dpp_xor1 x2, sel+dpp_xor2): lane cs holds
//      quad-sum of acc_{cs&3}
//   -> DPP row_ror:4 + row_ror:8 rotation-sum over the stride-4 coset
//      (preserves cs&3) = full row-dot, pure VALU, ZERO LDS swizzles.
// mv2 LDS: 5 -> 2 ops/wave (block 11 -> 8). Cost +~12 VALU/thread-iter.
// z re-laid at stride-24 sections: mv2 b128 reads land perfect 2-way banks
// (free, m136); mv1 writes stay conflict-free. mv1 phase unchanged.

constexpr double csqrt_(double x) {
  double g = x * 0.5 + 0.5;
  for (int i = 0; i < 40; ++i) g = 0.5 * (g + x / g);
  return g;
}
struct CoefT { float c[200]; };
constexpr CoefT make_coefs() {
  CoefT T{};
  double t = 1.0;
  for (int k = 0; k < 200; ++k) {
    double tn = 0.5 * (1.0 + csqrt_(1.0 + 4.0 * t * t));
    T.c[k] = (float)((t - 1.0) / tn);
    t = tn;
  }
  return T;
}
__device__ constexpr CoefT kCoef = make_coefs();

// DPP cross-lane helpers (pure VALU)
__device__ __forceinline__ float dpp_xor1(float v) {  // fetch lane^1 (quad_perm)
  return __int_as_float(__builtin_amdgcn_update_dpp(0, __float_as_int(v), 0xB1, 0xF, 0xF, true));
}
__device__ __forceinline__ float dpp_xor2(float v) {  // fetch lane^2
  return __int_as_float(__builtin_amdgcn_update_dpp(0, __float_as_int(v), 0x4E, 0xF, 0xF, true));
}
__device__ __forceinline__ float dpp_add_xor1(float v) { return v + dpp_xor1(v); }
__device__ __forceinline__ float dpp_add_xor2(float v) { return v + dpp_xor2(v); }
__device__ __forceinline__ float dpp_add_ror4(float v) {  // += lane+4 (mod 16-row)
  return v + __int_as_float(__builtin_amdgcn_update_dpp(0, __float_as_int(v), 0x124, 0xF, 0xF, true));
}
__device__ __forceinline__ float dpp_add_ror8(float v) {  // += lane+8 (mod 16-row)
  return v + __int_as_float(__builtin_amdgcn_update_dpp(0, __float_as_int(v), 0x128, 0xF, 0xF, true));
}
__device__ __forceinline__ float swz_add_xor4(float v) {  // lane^4 via LDS swizzle
  int r = __builtin_amdgcn_ds_swizzle(__float_as_int(v), 0x101F);
  return v + __int_as_float(r);
}

__global__ __launch_bounds__(512)
void qp_fista_kernel(const float* __restrict__ A,
                     const float* __restrict__ x,
                     const float* __restrict__ b,
                     float* __restrict__ out) {
  const int batch = blockIdx.x;
  const int tid = threadIdx.x;
  const int w = tid >> 6;   // wave 0..7

  __shared__ __align__(16) float tile[8192];  // A staging; later overlaid

  const float* Ag = A + (size_t)batch * 8192;

  // ---- stage A into LDS, coalesced float4 ----
  {
    const float4* Ag4 = (const float4*)Ag;
    float4* t4 = (float4*)tile;
#pragma unroll
    for (int k = 0; k < 4; ++k) t4[tid + k * 512] = Ag4[tid + k * 512];
  }
  __syncthreads();

  // ---- register views ----
  // mv2: 4x4 block. rows 4rg..4rg+3, cols 4cs..4cs+3.
  const int rg = tid >> 4;   // 32 row-groups
  const int cs = tid & 15;   // 16 col-slices (lane bits 0-3)
  float Ar4[16];             // Ar4[4k+t] = A[4rg+k][4cs+t]
  {
    const float4* t4 = (const float4*)tile;
#pragma unroll
    for (int k = 0; k < 4; ++k) {
      float4 v = t4[(4 * rg + k) * 16 + cs];
      Ar4[4 * k + 0] = v.x; Ar4[4 * k + 1] = v.y;
      Ar4[4 * k + 2] = v.z; Ar4[4 * k + 3] = v.w;
    }
  }
  // mv1 (unchanged): col c, row-eighth rq
  const int c  = tid >> 3;
  const int rq = tid & 7;
  float Ac[16];
#pragma unroll
  for (int i = 0; i < 16; ++i) Ac[i] = tile[(rq * 16 + i) * 64 + c];

  // sum of squares (Ar4 covers each A element exactly once across 512 threads)
  float ss = 0.f;
#pragma unroll
  for (int i = 0; i < 16; ++i) ss = fmaf(Ar4[i], Ar4[i], ss);
#pragma unroll
  for (int d = 1; d < 64; d <<= 1) ss += __shfl_xor(ss, d, 64);  // one-time

  __syncthreads();  // register extraction done; overlay small buffers

  float* zbuf = tile;         // 4 sections x 24 dw (z[0..63]); 2-way banks on b128
  float* ybuf = tile + 96;    // 8 sections x 20 dw (y[0..127])
  float* wsb  = tile + 272;   // 8 per-wave sum-of-squares

  if ((tid & 63) == 0) wsb[w] = ss;
  // this lane's final row after the merge-reduce: 4rg + (cs&3)
  const int myrow = 4 * rg + (tid & 3);
  const float breg = b[(size_t)batch * 128 + myrow];
  const float xreg = x[(size_t)batch * 64 + c];
  if (rq == 0) zbuf[(c >> 4) * 24 + (c & 15)] = xreg;  // z0 = primal(0) = x
  __syncthreads();

  float sum8 = 0.f;
#pragma unroll
  for (int i = 0; i < 8; ++i) sum8 += wsb[i];
  const float eta = 1.0f / fmaxf(8.0f * sum8, 1e-12f);  // ||Qinv||_F = 8
  const float yb0 = eta * breg;  // folded: y + eta*(acc-b) = fma(eta,acc,y-yb0)

  const float4* zs = (const float4*)(zbuf + (cs >> 2) * 24 + (cs & 3) * 4);
  const float4* ys = (const float4*)(ybuf + rq * 20);
  // y-writer: lanes cs<4 write row 4rg+cs -> section w, offset 4*(rg&3)+cs
  float* ywr = ybuf + w * 20 + 4 * (rg & 3) + (tid & 3);
  const bool ywrite = ((tid & 12) == 0);   // cs < 4
  float* zwr = zbuf + (c >> 4) * 24 + (c & 15);
  const bool sel0 = (tid & 1), sel1 = (tid & 2);

  float lam = 0.f, y = 0.f;

#pragma unroll 2
  for (int it = 0; it < 199; ++it) {
    const float coef = kCoef.c[it];

    // ---- mv2: (Az)[4rg+(cs&3)] — ONE b128 read, 16 FMA, DPP-only reduce ----
    __builtin_amdgcn_s_setprio(1);
    float4 zz = *zs;
    float a0 = Ar4[0] * zz.x, a1 = Ar4[4] * zz.x, a2 = Ar4[8] * zz.x, a3 = Ar4[12] * zz.x;
    a0 = fmaf(Ar4[1], zz.y, a0);  a1 = fmaf(Ar4[5], zz.y, a1);
    a2 = fmaf(Ar4[9], zz.y, a2);  a3 = fmaf(Ar4[13], zz.y, a3);
    a0 = fmaf(Ar4[2], zz.z, a0);  a1 = fmaf(Ar4[6], zz.z, a1);
    a2 = fmaf(Ar4[10], zz.z, a2); a3 = fmaf(Ar4[14], zz.z, a3);
    a0 = fmaf(Ar4[3], zz.w, a0);  a1 = fmaf(Ar4[7], zz.w, a1);
    a2 = fmaf(Ar4[11], zz.w, a2); a3 = fmaf(Ar4[15], zz.w, a3);
    // pair-swap butterfly: lane cs ends with quad-sum of acc_{cs&3}
    float u01 = sel0 ? a1 : a0, v01 = sel0 ? a0 : a1;
    u01 += dpp_xor1(v01);
    float u23 = sel0 ? a3 : a2, v23 = sel0 ? a2 : a3;
    u23 += dpp_xor1(v23);
    float s2 = sel1 ? u23 : u01, t2 = sel1 ? u01 : u23;
    s2 += dpp_xor2(t2);
    // rotation-sum across the 4 quads (stride-4 coset keeps cs&3): full row dot
    s2 = dpp_add_ror4(s2);
    s2 = dpp_add_ror8(s2);
    float ln = fmaxf(0.f, fmaf(eta, s2, y - yb0));
    float yn = fmaf(coef, ln - lam, ln);
    __builtin_amdgcn_s_setprio(0);
    lam = ln; y = yn;
    if (ywrite) *ywr = yn;
    __syncthreads();  // ybuf ready

    // ---- mv1: (A^T y)[c], unchanged ----
    __builtin_amdgcn_s_setprio(1);
    float q0 = 0.f, q1 = 0.f;
#pragma unroll
    for (int j = 0; j < 4; ++j) {
      float4 yy = ys[j];
      q0 = fmaf(Ac[4 * j + 0], yy.x, q0);
      q1 = fmaf(Ac[4 * j + 1], yy.y, q1);
      q0 = fmaf(Ac[4 * j + 2], yy.z, q0);
      q1 = fmaf(Ac[4 * j + 3], yy.w, q1);
    }
    float s = q0 + q1;
    s = dpp_add_xor1(s);
    s = dpp_add_xor2(s);
    s = swz_add_xor4(s);               // full col dot over 8 lanes
    __builtin_amdgcn_s_setprio(0);
    if (rq == 0) *zwr = xreg - s;      // z = x - A^T y
    __syncthreads();
  }

  // ---- peeled it = 199: write lam, final primal ----
  {
    float4 zz = *zs;
    float a0 = Ar4[0] * zz.x, a1 = Ar4[4] * zz.x, a2 = Ar4[8] * zz.x, a3 = Ar4[12] * zz.x;
    a0 = fmaf(Ar4[1], zz.y, a0);  a1 = fmaf(Ar4[5], zz.y, a1);
    a2 = fmaf(Ar4[9], zz.y, a2);  a3 = fmaf(Ar4[13], zz.y, a3);
    a0 = fmaf(Ar4[2], zz.z, a0);  a1 = fmaf(Ar4[6], zz.z, a1);
    a2 = fmaf(Ar4[10], zz.z, a2); a3 = fmaf(Ar4[14], zz.z, a3);
    a0 = fmaf(Ar4[3], zz.w, a0);  a1 = fmaf(Ar4[7], zz.w, a1);
    a2 = fmaf(Ar4[11], zz.w, a2); a3 = fmaf(Ar4[15], zz.w, a3);
    float u01 = sel0 ? a1 : a0, v01 = sel0 ? a0 : a1;
    u01 += dpp_xor1(v01);
    float u23 = sel0 ? a3 : a2, v23 = sel0 ? a2 : a3;
    u23 += dpp_xor1(v23);
    float s2 = sel1 ? u23 : u01, t2 = sel1 ? u01 : u23;
    s2 += dpp_xor2(t2);
    s2 = dpp_add_ror4(s2);
    s2 = dpp_add_ror8(s2);
    float ln = fmaxf(0.f, fmaf(eta, s2, y - yb0));
    if (ywrite) *ywr = ln;             // final lambda
    __syncthreads();

    float q0 = 0.f, q1 = 0.f;
#pragma unroll
    for (int j = 0; j < 4; ++j) {
      float4 yy = ys[j];
      q0 = fmaf(Ac[4 * j + 0], yy.x, q0);
      q1 = fmaf(Ac[4 * j + 1], yy.y, q1);
      q0 = fmaf(Ac[4 * j + 2], yy.z, q0);
      q1 = fmaf(Ac[4 * j + 3], yy.w, q1);
    }
    float s = q0 + q1;
    s = dpp_add_xor1(s);
    s = dpp_add_xor2(s);
    s = swz_add_xor4(s);
    if (rq == 0) *zwr = xreg - s;      // z* = x - A^T lam
    __syncthreads();
  }

  if (tid < 64) {
    out[(size_t)batch * 64 + tid] = zbuf[(tid >> 4) * 24 + (tid & 15)];
  }
}

extern "C" void kernel_launch(void* const* d_in, const int* in_sizes, int n_in,
                              void* d_out, int out_size, void* d_ws, size_t ws_size,
                              hipStream_t stream) {
  // setup_inputs order: Q (ignored: identity), A, x, b
  const float* A = (const float*)d_in[1];
  const float* x = (const float*)d_in[2];
  const float* b = (const float*)d_in[3];
  float* out = (float*)d_out;
  qp_fista_kernel<<<dim3(8192), dim3(512), 0, stream>>>(A, x, b, out);
}

// Round 20
// 980.426 us; speedup vs baseline: 1.0690x; 1.0208x over previous
//
#include <hip/hip_runtime.h>

// Batched QP via FISTA on the dual, Q = I (reference hardcodes eye(64)).
//
// R20 = R19 (best: rocprof ~1204us, harness 1001us) + mv1 swizzle->DPP.
// R19 confirmed the LDS-pipe/critical-path theory: dropping 3 LDS ops/wave
// in mv2 won -3.5% even though the new z-read is inherently 2-way bank-
// aliased (16 distinct b128 addrs = 64 bank-slots / 32 banks; 2-way ~free).
// Remaining LDS op on mv1's critical path: ds_swizzle xor4 (lgkmcnt wait).
// The reduce group {8c..8c+7} is exactly a DPP HALF-ROW: after xor1+xor2
// quad-sums, row_half_mirror (0x141, i<->i^7) add completes the 8-sum in
// pure VALU. Block LDS ops 8 -> 7 per wave-iter, ~25cy off the chain.

constexpr double csqrt_(double x) {
  double g = x * 0.5 + 0.5;
  for (int i = 0; i < 40; ++i) g = 0.5 * (g + x / g);
  return g;
}
struct CoefT { float c[200]; };
constexpr CoefT make_coefs() {
  CoefT T{};
  double t = 1.0;
  for (int k = 0; k < 200; ++k) {
    double tn = 0.5 * (1.0 + csqrt_(1.0 + 4.0 * t * t));
    T.c[k] = (float)((t - 1.0) / tn);
    t = tn;
  }
  return T;
}
__device__ constexpr CoefT kCoef = make_coefs();

// DPP cross-lane helpers (pure VALU)
__device__ __forceinline__ float dpp_xor1(float v) {  // fetch lane^1 (quad_perm)
  return __int_as_float(__builtin_amdgcn_update_dpp(0, __float_as_int(v), 0xB1, 0xF, 0xF, true));
}
__device__ __forceinline__ float dpp_xor2(float v) {  // fetch lane^2
  return __int_as_float(__builtin_amdgcn_update_dpp(0, __float_as_int(v), 0x4E, 0xF, 0xF, true));
}
__device__ __forceinline__ float dpp_add_xor1(float v) { return v + dpp_xor1(v); }
__device__ __forceinline__ float dpp_add_xor2(float v) { return v + dpp_xor2(v); }
__device__ __forceinline__ float dpp_add_ror4(float v) {  // += lane+4 (mod 16-row)
  return v + __int_as_float(__builtin_amdgcn_update_dpp(0, __float_as_int(v), 0x124, 0xF, 0xF, true));
}
__device__ __forceinline__ float dpp_add_ror8(float v) {  // += lane+8 (mod 16-row)
  return v + __int_as_float(__builtin_amdgcn_update_dpp(0, __float_as_int(v), 0x128, 0xF, 0xF, true));
}
__device__ __forceinline__ float dpp_add_hmirror(float v) {  // += lane (i^7 in half-row)
  return v + __int_as_float(__builtin_amdgcn_update_dpp(0, __float_as_int(v), 0x141, 0xF, 0xF, true));
}

__global__ __launch_bounds__(512)
void qp_fista_kernel(const float* __restrict__ A,
                     const float* __restrict__ x,
                     const float* __restrict__ b,
                     float* __restrict__ out) {
  const int batch = blockIdx.x;
  const int tid = threadIdx.x;
  const int w = tid >> 6;   // wave 0..7

  __shared__ __align__(16) float tile[8192];  // A staging; later overlaid

  const float* Ag = A + (size_t)batch * 8192;

  // ---- stage A into LDS, coalesced float4 ----
  {
    const float4* Ag4 = (const float4*)Ag;
    float4* t4 = (float4*)tile;
#pragma unroll
    for (int k = 0; k < 4; ++k) t4[tid + k * 512] = Ag4[tid + k * 512];
  }
  __syncthreads();

  // ---- register views ----
  // mv2: 4x4 block. rows 4rg..4rg+3, cols 4cs..4cs+3.
  const int rg = tid >> 4;   // 32 row-groups
  const int cs = tid & 15;   // 16 col-slices (lane bits 0-3)
  float Ar4[16];             // Ar4[4k+t] = A[4rg+k][4cs+t]
  {
    const float4* t4 = (const float4*)tile;
#pragma unroll
    for (int k = 0; k < 4; ++k) {
      float4 v = t4[(4 * rg + k) * 16 + cs];
      Ar4[4 * k + 0] = v.x; Ar4[4 * k + 1] = v.y;
      Ar4[4 * k + 2] = v.z; Ar4[4 * k + 3] = v.w;
    }
  }
  // mv1 (unchanged): col c, row-eighth rq
  const int c  = tid >> 3;
  const int rq = tid & 7;
  float Ac[16];
#pragma unroll
  for (int i = 0; i < 16; ++i) Ac[i] = tile[(rq * 16 + i) * 64 + c];

  // sum of squares (Ar4 covers each A element exactly once across 512 threads)
  float ss = 0.f;
#pragma unroll
  for (int i = 0; i < 16; ++i) ss = fmaf(Ar4[i], Ar4[i], ss);
#pragma unroll
  for (int d = 1; d < 64; d <<= 1) ss += __shfl_xor(ss, d, 64);  // one-time

  __syncthreads();  // register extraction done; overlay small buffers

  float* zbuf = tile;         // 4 sections x 24 dw (z[0..63]); 2-way banks on b128
  float* ybuf = tile + 96;    // 8 sections x 20 dw (y[0..127])
  float* wsb  = tile + 272;   // 8 per-wave sum-of-squares

  if ((tid & 63) == 0) wsb[w] = ss;
  // this lane's final row after the merge-reduce: 4rg + (cs&3)
  const int myrow = 4 * rg + (tid & 3);
  const float breg = b[(size_t)batch * 128 + myrow];
  const float xreg = x[(size_t)batch * 64 + c];
  if (rq == 0) zbuf[(c >> 4) * 24 + (c & 15)] = xreg;  // z0 = primal(0) = x
  __syncthreads();

  float sum8 = 0.f;
#pragma unroll
  for (int i = 0; i < 8; ++i) sum8 += wsb[i];
  const float eta = 1.0f / fmaxf(8.0f * sum8, 1e-12f);  // ||Qinv||_F = 8
  const float yb0 = eta * breg;  // folded: y + eta*(acc-b) = fma(eta,acc,y-yb0)

  const float4* zs = (const float4*)(zbuf + (cs >> 2) * 24 + (cs & 3) * 4);
  const float4* ys = (const float4*)(ybuf + rq * 20);
  // y-writer: lanes cs<4 write row 4rg+cs -> section w, offset 4*(rg&3)+cs
  float* ywr = ybuf + w * 20 + 4 * (rg & 3) + (tid & 3);
  const bool ywrite = ((tid & 12) == 0);   // cs < 4
  float* zwr = zbuf + (c >> 4) * 24 + (c & 15);
  const bool sel0 = (tid & 1), sel1 = (tid & 2);

  float lam = 0.f, y = 0.f;

#pragma unroll 2
  for (int it = 0; it < 199; ++it) {
    const float coef = kCoef.c[it];

    // ---- mv2: (Az)[4rg+(cs&3)] — ONE b128 read, 16 FMA, DPP-only reduce ----
    __builtin_amdgcn_s_setprio(1);
    float4 zz = *zs;
    float a0 = Ar4[0] * zz.x, a1 = Ar4[4] * zz.x, a2 = Ar4[8] * zz.x, a3 = Ar4[12] * zz.x;
    a0 = fmaf(Ar4[1], zz.y, a0);  a1 = fmaf(Ar4[5], zz.y, a1);
    a2 = fmaf(Ar4[9], zz.y, a2);  a3 = fmaf(Ar4[13], zz.y, a3);
    a0 = fmaf(Ar4[2], zz.z, a0);  a1 = fmaf(Ar4[6], zz.z, a1);
    a2 = fmaf(Ar4[10], zz.z, a2); a3 = fmaf(Ar4[14], zz.z, a3);
    a0 = fmaf(Ar4[3], zz.w, a0);  a1 = fmaf(Ar4[7], zz.w, a1);
    a2 = fmaf(Ar4[11], zz.w, a2); a3 = fmaf(Ar4[15], zz.w, a3);
    // pair-swap butterfly: lane cs ends with quad-sum of acc_{cs&3}
    float u01 = sel0 ? a1 : a0, v01 = sel0 ? a0 : a1;
    u01 += dpp_xor1(v01);
    float u23 = sel0 ? a3 : a2, v23 = sel0 ? a2 : a3;
    u23 += dpp_xor1(v23);
    float s2 = sel1 ? u23 : u01, t2 = sel1 ? u01 : u23;
    s2 += dpp_xor2(t2);
    // rotation-sum across the 4 quads (stride-4 coset keeps cs&3): full row dot
    s2 = dpp_add_ror4(s2);
    s2 = dpp_add_ror8(s2);
    float ln = fmaxf(0.f, fmaf(eta, s2, y - yb0));
    float yn = fmaf(coef, ln - lam, ln);
    __builtin_amdgcn_s_setprio(0);
    lam = ln; y = yn;
    if (ywrite) *ywr = yn;
    __syncthreads();  // ybuf ready

    // ---- mv1: (A^T y)[c] — 4 b128 reads, DPP-ONLY 8-lane reduce ----
    __builtin_amdgcn_s_setprio(1);
    float q0 = 0.f, q1 = 0.f;
#pragma unroll
    for (int j = 0; j < 4; ++j) {
      float4 yy = ys[j];
      q0 = fmaf(Ac[4 * j + 0], yy.x, q0);
      q1 = fmaf(Ac[4 * j + 1], yy.y, q1);
      q0 = fmaf(Ac[4 * j + 2], yy.z, q0);
      q1 = fmaf(Ac[4 * j + 3], yy.w, q1);
    }
    float s = q0 + q1;
    s = dpp_add_xor1(s);
    s = dpp_add_xor2(s);
    s = dpp_add_hmirror(s);            // 8-lane sum, pure VALU (was ds_swizzle)
    __builtin_amdgcn_s_setprio(0);
    if (rq == 0) *zwr = xreg - s;      // z = x - A^T y
    __syncthreads();
  }

  // ---- peeled it = 199: write lam, final primal ----
  {
    float4 zz = *zs;
    float a0 = Ar4[0] * zz.x, a1 = Ar4[4] * zz.x, a2 = Ar4[8] * zz.x, a3 = Ar4[12] * zz.x;
    a0 = fmaf(Ar4[1], zz.y, a0);  a1 = fmaf(Ar4[5], zz.y, a1);
    a2 = fmaf(Ar4[9], zz.y, a2);  a3 = fmaf(Ar4[13], zz.y, a3);
    a0 = fmaf(Ar4[2], zz.z, a0);  a1 = fmaf(Ar4[6], zz.z, a1);
    a2 = fmaf(Ar4[10], zz.z, a2); a3 = fmaf(Ar4[14], zz.z, a3);
    a0 = fmaf(Ar4[3], zz.w, a0);  a1 = fmaf(Ar4[7], zz.w, a1);
    a2 = fmaf(Ar4[11], zz.w, a2); a3 = fmaf(Ar4[15], zz.w, a3);
    float u01 = sel0 ? a1 : a0, v01 = sel0 ? a0 : a1;
    u01 += dpp_xor1(v01);
    float u23 = sel0 ? a3 : a2, v23 = sel0 ? a2 : a3;
    u23 += dpp_xor1(v23);
    float s2 = sel1 ? u23 : u01, t2 = sel1 ? u01 : u23;
    s2 += dpp_xor2(t2);
    s2 = dpp_add_ror4(s2);
    s2 = dpp_add_ror8(s2);
    float ln = fmaxf(0.f, fmaf(eta, s2, y - yb0));
    if (ywrite) *ywr = ln;             // final lambda
    __syncthreads();

    float q0 = 0.f, q1 = 0.f;
#pragma unroll
    for (int j = 0; j < 4; ++j) {
      float4 yy = ys[j];
      q0 = fmaf(Ac[4 * j + 0], yy.x, q0);
      q1 = fmaf(Ac[4 * j + 1], yy.y, q1);
      q0 = fmaf(Ac[4 * j + 2], yy.z, q0);
      q1 = fmaf(Ac[4 * j + 3], yy.w, q1);
    }
    float s = q0 + q1;
    s = dpp_add_xor1(s);
    s = dpp_add_xor2(s);
    s = dpp_add_hmirror(s);
    if (rq == 0) *zwr = xreg - s;      // z* = x - A^T lam
    __syncthreads();
  }

  if (tid < 64) {
    out[(size_t)batch * 64 + tid] = zbuf[(tid >> 4) * 24 + (tid & 15)];
  }
}

extern "C" void kernel_launch(void* const* d_in, const int* in_sizes, int n_in,
                              void* d_out, int out_size, void* d_ws, size_t ws_size,
                              hipStream_t stream) {
  // setup_inputs order: Q (ignored: identity), A, x, b
  const float* A = (const float*)d_in[1];
  const float* x = (const float*)d_in[2];
  const float* b = (const float*)d_in[3];
  float* out = (float*)d_out;
  qp_fista_kernel<<<dim3(8192), dim3(512), 0, stream>>>(A, x, b, out);
}

// Round 21
// 958.053 us; speedup vs baseline: 1.0939x; 1.0234x over previous
//
#include <hip/hip_runtime.h>

// Batched QP via FISTA on the dual, Q = I (reference hardcodes eye(64)).
//
// R21 = R20 (rocprof ~1181us, harness 980us) + mv1 read-halving.
// Calibration from R17->R20: each LDS op removed from the per-iter critical
// path is worth ~20-25us. mv1 still has 4 b128 y-reads; re-map it like R19's
// mv2: thread (grp=tid>>4, l=tid&15) owns A[8l..8l+7][2grp..2grp+1] ->
// its 8 y-values are contiguous -> TWO b128 reads. Col-partials merge via
// pair-swap + dpp_xor1 (lane parity = col), then row_ror:2/4/8 sums the 8
// same-parity lanes of the 16-lane DPP row (pure VALU).
// y re-laid per-octet: y[m] -> ybuf[(m>>3)*36 + (m&7)]; reads/writes land
// 2-way bank-aliased (free, m136). LDS ops/wave-iter: 7 -> 5.

constexpr double csqrt_(double x) {
  double g = x * 0.5 + 0.5;
  for (int i = 0; i < 40; ++i) g = 0.5 * (g + x / g);
  return g;
}
struct CoefT { float c[200]; };
constexpr CoefT make_coefs() {
  CoefT T{};
  double t = 1.0;
  for (int k = 0; k < 200; ++k) {
    double tn = 0.5 * (1.0 + csqrt_(1.0 + 4.0 * t * t));
    T.c[k] = (float)((t - 1.0) / tn);
    t = tn;
  }
  return T;
}
__device__ constexpr CoefT kCoef = make_coefs();

// DPP cross-lane helpers (pure VALU)
__device__ __forceinline__ float dpp_xor1(float v) {  // fetch lane^1 (quad_perm)
  return __int_as_float(__builtin_amdgcn_update_dpp(0, __float_as_int(v), 0xB1, 0xF, 0xF, true));
}
__device__ __forceinline__ float dpp_xor2(float v) {  // fetch lane^2
  return __int_as_float(__builtin_amdgcn_update_dpp(0, __float_as_int(v), 0x4E, 0xF, 0xF, true));
}
__device__ __forceinline__ float dpp_add_xor1(float v) { return v + dpp_xor1(v); }
__device__ __forceinline__ float dpp_add_xor2(float v) { return v + dpp_xor2(v); }
__device__ __forceinline__ float dpp_add_ror2(float v) {  // += rotated-by-2 (16-row)
  return v + __int_as_float(__builtin_amdgcn_update_dpp(0, __float_as_int(v), 0x122, 0xF, 0xF, true));
}
__device__ __forceinline__ float dpp_add_ror4(float v) {  // += rotated-by-4
  return v + __int_as_float(__builtin_amdgcn_update_dpp(0, __float_as_int(v), 0x124, 0xF, 0xF, true));
}
__device__ __forceinline__ float dpp_add_ror8(float v) {  // += rotated-by-8
  return v + __int_as_float(__builtin_amdgcn_update_dpp(0, __float_as_int(v), 0x128, 0xF, 0xF, true));
}

__global__ __launch_bounds__(512)
void qp_fista_kernel(const float* __restrict__ A,
                     const float* __restrict__ x,
                     const float* __restrict__ b,
                     float* __restrict__ out) {
  const int batch = blockIdx.x;
  const int tid = threadIdx.x;
  const int w = tid >> 6;   // wave 0..7

  __shared__ __align__(16) float tile[8192];  // A staging; later overlaid

  const float* Ag = A + (size_t)batch * 8192;

  // ---- stage A into LDS, coalesced float4 ----
  {
    const float4* Ag4 = (const float4*)Ag;
    float4* t4 = (float4*)tile;
#pragma unroll
    for (int k = 0; k < 4; ++k) t4[tid + k * 512] = Ag4[tid + k * 512];
  }
  __syncthreads();

  // ---- register views ----
  // mv2: 4x4 block. rows 4rg..4rg+3, cols 4cs..4cs+3.
  const int rg = tid >> 4;   // 32 row-groups
  const int cs = tid & 15;   // 16 col-slices (lane bits 0-3)
  float Ar4[16];             // Ar4[4k+t] = A[4rg+k][4cs+t]
  {
    const float4* t4 = (const float4*)tile;
#pragma unroll
    for (int k = 0; k < 4; ++k) {
      float4 v = t4[(4 * rg + k) * 16 + cs];
      Ar4[4 * k + 0] = v.x; Ar4[4 * k + 1] = v.y;
      Ar4[4 * k + 2] = v.z; Ar4[4 * k + 3] = v.w;
    }
  }
  // mv1: 8x2 block. rows 8l..8l+7, cols 2grp..2grp+1. (grp==rg, l==cs)
  float Ac2[16];             // Ac2[i]=A[8l+i][2grp], Ac2[8+i]=A[8l+i][2grp+1]
#pragma unroll
  for (int i = 0; i < 8; ++i) {
    Ac2[i]     = tile[(8 * cs + i) * 64 + 2 * rg + 0];
    Ac2[8 + i] = tile[(8 * cs + i) * 64 + 2 * rg + 1];
  }

  // sum of squares (Ar4 covers each A element exactly once across 512 threads)
  float ss = 0.f;
#pragma unroll
  for (int i = 0; i < 16; ++i) ss = fmaf(Ar4[i], Ar4[i], ss);
#pragma unroll
  for (int d = 1; d < 64; d <<= 1) ss += __shfl_xor(ss, d, 64);  // one-time

  __syncthreads();  // register extraction done; overlay small buffers

  float* zbuf = tile;         // 4 sections x 24 dw (z[0..63]); 2-way banks on b128
  float* ybuf = tile + 96;    // 16 sections x 36 dw: y[m] @ (m>>3)*36+(m&7)
  float* wsb  = tile + 672;   // 8 per-wave sum-of-squares

  if ((tid & 63) == 0) wsb[w] = ss;
  // mv2: this lane's final row after the merge-reduce: 4rg + (cs&3)
  const int myrow = 4 * rg + (tid & 3);
  const float breg = b[(size_t)batch * 128 + myrow];
  // mv1: this lane's final col after the reduce: 2rg + (cs&1)
  const int myc = 2 * rg + (tid & 1);
  const float xreg = x[(size_t)batch * 64 + myc];
  if (tid < 64) zbuf[(tid >> 4) * 24 + (tid & 15)] = x[(size_t)batch * 64 + tid];
  __syncthreads();

  float sum8 = 0.f;
#pragma unroll
  for (int i = 0; i < 8; ++i) sum8 += wsb[i];
  const float eta = 1.0f / fmaxf(8.0f * sum8, 1e-12f);  // ||Qinv||_F = 8
  const float yb0 = eta * breg;  // folded: y + eta*(acc-b) = fma(eta,acc,y-yb0)

  // mv2 pointers: read z[4cs..4cs+3]; write y[4rg+cs] (cs<4) to octet layout
  const float4* zs = (const float4*)(zbuf + (cs >> 2) * 24 + (cs & 3) * 4);
  // y[m], m=4rg+cs (cs<4): (m>>3)=rg>>1, (m&7)=4*(rg&1)+cs
  float* ywr = ybuf + (rg >> 1) * 36 + 4 * (rg & 1) + (tid & 3);
  const bool ywrite = ((tid & 12) == 0);   // cs < 4
  // mv1 pointers: read y[8cs..8cs+7] (two b128); write z[myc] (cs<2)
  const float4* ys = (const float4*)(ybuf + cs * 36);
  float* zwr = zbuf + (myc >> 4) * 24 + (myc & 15);
  const bool zwrite = ((tid & 14) == 0);   // cs < 2
  const bool sel0 = (tid & 1), sel1 = (tid & 2);

  float lam = 0.f, y = 0.f;

#pragma unroll 2
  for (int it = 0; it < 199; ++it) {
    const float coef = kCoef.c[it];

    // ---- mv2: (Az)[4rg+(cs&3)] — ONE b128 read, 16 FMA, DPP-only reduce ----
    __builtin_amdgcn_s_setprio(1);
    float4 zz = *zs;
    float a0 = Ar4[0] * zz.x, a1 = Ar4[4] * zz.x, a2 = Ar4[8] * zz.x, a3 = Ar4[12] * zz.x;
    a0 = fmaf(Ar4[1], zz.y, a0);  a1 = fmaf(Ar4[5], zz.y, a1);
    a2 = fmaf(Ar4[9], zz.y, a2);  a3 = fmaf(Ar4[13], zz.y, a3);
    a0 = fmaf(Ar4[2], zz.z, a0);  a1 = fmaf(Ar4[6], zz.z, a1);
    a2 = fmaf(Ar4[10], zz.z, a2); a3 = fmaf(Ar4[14], zz.z, a3);
    a0 = fmaf(Ar4[3], zz.w, a0);  a1 = fmaf(Ar4[7], zz.w, a1);
    a2 = fmaf(Ar4[11], zz.w, a2); a3 = fmaf(Ar4[15], zz.w, a3);
    // pair-swap butterfly: lane cs ends with quad-sum of acc_{cs&3}
    float u01 = sel0 ? a1 : a0, v01 = sel0 ? a0 : a1;
    u01 += dpp_xor1(v01);
    float u23 = sel0 ? a3 : a2, v23 = sel0 ? a2 : a3;
    u23 += dpp_xor1(v23);
    float s2 = sel1 ? u23 : u01, t2 = sel1 ? u01 : u23;
    s2 += dpp_xor2(t2);
    // rotation-sum across the 4 quads (stride-4 coset keeps cs&3)
    s2 = dpp_add_ror4(s2);
    s2 = dpp_add_ror8(s2);
    float ln = fmaxf(0.f, fmaf(eta, s2, y - yb0));
    float yn = fmaf(coef, ln - lam, ln);
    __builtin_amdgcn_s_setprio(0);
    lam = ln; y = yn;
    if (ywrite) *ywr = yn;
    __syncthreads();  // ybuf ready

    // ---- mv1: (A^T y)[2rg+(cs&1)] — TWO b128 reads, 16 FMA, DPP reduce ----
    __builtin_amdgcn_s_setprio(1);
    float4 y0 = ys[0], y1 = ys[1];
    float q0, q1;
    q0 = Ac2[0] * y0.x;            q1 = Ac2[8] * y0.x;
    q0 = fmaf(Ac2[1], y0.y, q0);   q1 = fmaf(Ac2[9],  y0.y, q1);
    q0 = fmaf(Ac2[2], y0.z, q0);   q1 = fmaf(Ac2[10], y0.z, q1);
    q0 = fmaf(Ac2[3], y0.w, q0);   q1 = fmaf(Ac2[11], y0.w, q1);
    q0 = fmaf(Ac2[4], y1.x, q0);   q1 = fmaf(Ac2[12], y1.x, q1);
    q0 = fmaf(Ac2[5], y1.y, q0);   q1 = fmaf(Ac2[13], y1.y, q1);
    q0 = fmaf(Ac2[6], y1.z, q0);   q1 = fmaf(Ac2[14], y1.z, q1);
    q0 = fmaf(Ac2[7], y1.w, q0);   q1 = fmaf(Ac2[15], y1.w, q1);
    // pair-swap: lane parity picks its col; xor1 merges neighbor's partial
    float uq = sel0 ? q1 : q0, vq = sel0 ? q0 : q1;
    uq += dpp_xor1(vq);
    // sum the 8 same-parity lanes of the 16-lane row (rotation Kogge-Stone)
    uq = dpp_add_ror2(uq);
    uq = dpp_add_ror4(uq);
    uq = dpp_add_ror8(uq);
    __builtin_amdgcn_s_setprio(0);
    if (zwrite) *zwr = xreg - uq;      // z = x - A^T y
    __syncthreads();
  }

  // ---- peeled it = 199: write lam, final primal ----
  {
    float4 zz = *zs;
    float a0 = Ar4[0] * zz.x, a1 = Ar4[4] * zz.x, a2 = Ar4[8] * zz.x, a3 = Ar4[12] * zz.x;
    a0 = fmaf(Ar4[1], zz.y, a0);  a1 = fmaf(Ar4[5], zz.y, a1);
    a2 = fmaf(Ar4[9], zz.y, a2);  a3 = fmaf(Ar4[13], zz.y, a3);
    a0 = fmaf(Ar4[2], zz.z, a0);  a1 = fmaf(Ar4[6], zz.z, a1);
    a2 = fmaf(Ar4[10], zz.z, a2); a3 = fmaf(Ar4[14], zz.z, a3);
    a0 = fmaf(Ar4[3], zz.w, a0);  a1 = fmaf(Ar4[7], zz.w, a1);
    a2 = fmaf(Ar4[11], zz.w, a2); a3 = fmaf(Ar4[15], zz.w, a3);
    float u01 = sel0 ? a1 : a0, v01 = sel0 ? a0 : a1;
    u01 += dpp_xor1(v01);
    float u23 = sel0 ? a3 : a2, v23 = sel0 ? a2 : a3;
    u23 += dpp_xor1(v23);
    float s2 = sel1 ? u23 : u01, t2 = sel1 ? u01 : u23;
    s2 += dpp_xor2(t2);
    s2 = dpp_add_ror4(s2);
    s2 = dpp_add_ror8(s2);
    float ln = fmaxf(0.f, fmaf(eta, s2, y - yb0));
    if (ywrite) *ywr = ln;             // final lambda
    __syncthreads();

    float4 y0 = ys[0], y1 = ys[1];
    float q0, q1;
    q0 = Ac2[0] * y0.x;            q1 = Ac2[8] * y0.x;
    q0 = fmaf(Ac2[1], y0.y, q0);   q1 = fmaf(Ac2[9],  y0.y, q1);
    q0 = fmaf(Ac2[2], y0.z, q0);   q1 = fmaf(Ac2[10], y0.z, q1);
    q0 = fmaf(Ac2[3], y0.w, q0);   q1 = fmaf(Ac2[11], y0.w, q1);
    q0 = fmaf(Ac2[4], y1.x, q0);   q1 = fmaf(Ac2[12], y1.x, q1);
    q0 = fmaf(Ac2[5], y1.y, q0);   q1 = fmaf(Ac2[13], y1.y, q1);
    q0 = fmaf(Ac2[6], y1.z, q0);   q1 = fmaf(Ac2[14], y1.z, q1);
    q0 = fmaf(Ac2[7], y1.w, q0);   q1 = fmaf(Ac2[15], y1.w, q1);
    float uq = sel0 ? q1 : q0, vq = sel0 ? q0 : q1;
    uq += dpp_xor1(vq);
    uq = dpp_add_ror2(uq);
    uq = dpp_add_ror4(uq);
    uq = dpp_add_ror8(uq);
    if (zwrite) *zwr = xreg - uq;      // z* = x - A^T lam
    __syncthreads();
  }

  if (tid < 64) {
    out[(size_t)batch * 64 + tid] = zbuf[(tid >> 4) * 24 + (tid & 15)];
  }
}

extern "C" void kernel_launch(void* const* d_in, const int* in_sizes, int n_in,
                              void* d_out, int out_size, void* d_ws, size_t ws_size,
                              hipStream_t stream) {
  // setup_inputs order: Q (ignored: identity), A, x, b
  const float* A = (const float*)d_in[1];
  const float* x = (const float*)d_in[2];
  const float* b = (const float*)d_in[3];
  float* out = (float*)d_out;
  qp_fista_kernel<<<dim3(8192), dim3(512), 0, stream>>>(A, x, b, out);
}